// Round 10
// baseline (719.460 us; speedup 1.0000x reference)
//
#include <hip/hip_runtime.h>

// OnlineDenoisingAutoencoder: LSTM(B=2048, T=2048, in=1, proj=16, H=32)
// R10 = R6 (champion, 670us) + loop-carried-chain cuts:
//   - dot chains depth 8 -> 4 (4 accums/gate, stride-4, tree combine)
//   - accum seeding via fmaf(xv,a,c) + inline-0 starts
//   - branchless x prefetch index
// Reverted R9's f16 trans (cost +50 cyc/step marshaling; f32 trans are fast).
// Layout (R6): 2 batches/wave (half=batch, j=lane&31), all 4 gates per lane,
// v_dot2_f32_f16 dots (fp16 weights/h, fp32 accum), fp32 cell state, h via
// per-wave LDS (write + 4x ds_read_b128, no syncthreads), DPP output reduce.
// 1024 waves. History: R2 864 (fp32); R3 pk_fma not 2x (996); R4 readlane
// (1034); R6 670; R7 reg-gather (731, proved stall != LDS); R8 TLP=2 dup
// (875); R9 f16 trans (716).

#define BB 2048
#define TT 2048
#define HH 32

typedef _Float16 h2 __attribute__((ext_vector_type(2)));

__device__ __forceinline__ float gate_eval(float x, float m, float a, float b) {
    // a * (1 / (1 + 2^(m*x))) + b ; sigmoid: m=-log2e,a=1,b=0 ; tanh: m=-2log2e,a=2,b=-1
    float e = __builtin_amdgcn_exp2f(x * m);
    float r = __builtin_amdgcn_rcpf(1.0f + e);
    return fmaf(a, r, b);
}

template <int CTRL>
__device__ __forceinline__ float dpp_add(float v) {
    int s = __builtin_amdgcn_update_dpp(0, __float_as_int(v), CTRL, 0xf, 0xf, true);
    return v + __int_as_float(s);
}

struct HVec { h2 v[16]; };

__device__ __forceinline__ HVec gather_h(const _Float16* base) {
    const float4* p = (const float4*)base;   // 64 B = 4 x ds_read_b128 (broadcast)
    float4 q0 = p[0], q1 = p[1], q2 = p[2], q3 = p[3];
    HVec r;
    r.v[0]  = __builtin_bit_cast(h2, q0.x); r.v[1]  = __builtin_bit_cast(h2, q0.y);
    r.v[2]  = __builtin_bit_cast(h2, q0.z); r.v[3]  = __builtin_bit_cast(h2, q0.w);
    r.v[4]  = __builtin_bit_cast(h2, q1.x); r.v[5]  = __builtin_bit_cast(h2, q1.y);
    r.v[6]  = __builtin_bit_cast(h2, q1.z); r.v[7]  = __builtin_bit_cast(h2, q1.w);
    r.v[8]  = __builtin_bit_cast(h2, q2.x); r.v[9]  = __builtin_bit_cast(h2, q2.y);
    r.v[10] = __builtin_bit_cast(h2, q2.z); r.v[11] = __builtin_bit_cast(h2, q2.w);
    r.v[12] = __builtin_bit_cast(h2, q3.x); r.v[13] = __builtin_bit_cast(h2, q3.y);
    r.v[14] = __builtin_bit_cast(h2, q3.z); r.v[15] = __builtin_bit_cast(h2, q3.w);
    return r;
}

__global__ __launch_bounds__(256) void lstm_fused_kernel(
    const float* __restrict__ x_seq,  // [B,T,1]
    const float* __restrict__ Wp,     // [16,1]
    const float* __restrict__ bp,     // [16]
    const float* __restrict__ W_ih,   // [128,16]
    const float* __restrict__ W_hh,   // [128,32]
    const float* __restrict__ b_ih,   // [128]
    const float* __restrict__ b_hh,   // [128]
    const float* __restrict__ Wo,     // [1,32]
    const float* __restrict__ bo,     // [1]
    float* __restrict__ out)          // [B,T,1] fp32
{
    const int tid  = threadIdx.x;
    const int wave = tid >> 6;
    const int lane = tid & 63;
    const int half = lane >> 5;      // which of the wave's 2 batch elements
    const int j    = lane & 31;      // hidden index this lane owns
    const int b    = blockIdx.x * 8 + wave * 2 + half;

    // PyTorch gate row order: i=[0,32), f=[32,64), g=[64,96), o=[96,128)
    const int rI = j, rF = HH + j, rG = 2 * HH + j, rO = 3 * HH + j;

    // ---- W_hh rows (4 gates) into registers as packed fp16 pairs ----
    h2 wI[16], wF[16], wG[16], wO[16];
    {
        const float2* pI = (const float2*)(W_hh + rI * HH);
        const float2* pF = (const float2*)(W_hh + rF * HH);
        const float2* pG = (const float2*)(W_hh + rG * HH);
        const float2* pO = (const float2*)(W_hh + rO * HH);
#pragma unroll
        for (int k = 0; k < 16; ++k) {
            float2 a = pI[k], f = pF[k], g = pG[k], o = pO[k];
            wI[k].x = (_Float16)a.x; wI[k].y = (_Float16)a.y;
            wF[k].x = (_Float16)f.x; wF[k].y = (_Float16)f.y;
            wG[k].x = (_Float16)g.x; wG[k].y = (_Float16)g.y;
            wO[k].x = (_Float16)o.x; wO[k].y = (_Float16)o.y;
        }
    }

    // ---- collapse input pipeline: pre-act = dot + x*a + c (INPUT_DIM==1) ----
    float aI = 0.f, cI = 0.f, aF = 0.f, cF = 0.f;
    float aG = 0.f, cG = 0.f, aO = 0.f, cO = 0.f;
#pragma unroll
    for (int p = 0; p < 16; ++p) {
        float wpv = Wp[p], bpv = bp[p];
        float wi = W_ih[rI * 16 + p], wf = W_ih[rF * 16 + p];
        float wg = W_ih[rG * 16 + p], wo_ = W_ih[rO * 16 + p];
        aI = fmaf(wi, wpv, aI);  cI = fmaf(wi, bpv, cI);
        aF = fmaf(wf, wpv, aF);  cF = fmaf(wf, bpv, cF);
        aG = fmaf(wg, wpv, aG);  cG = fmaf(wg, bpv, cG);
        aO = fmaf(wo_, wpv, aO); cO = fmaf(wo_, bpv, cO);
    }
    cI += b_ih[rI] + b_hh[rI];
    cF += b_ih[rF] + b_hh[rF];
    cG += b_ih[rG] + b_hh[rG];
    cO += b_ih[rO] + b_hh[rO];

    const float LOG2E = 1.44269504088896340736f;
    const float woj = Wo[j];
    const float bo0 = bo[0];

    // per-(wave,batch) h buffer, fp16, 64 B each
    __shared__ __align__(16) _Float16 hsh[4][2][HH];
    _Float16* hbase = &hsh[wave][half][0];
    hbase[j] = (_Float16)0.0f;

    float c = 0.0f;
    const float* xp = x_seq + (size_t)b * TT;
    float* op = out + (size_t)b * TT;

    HVec hcur = gather_h(hbase);            // zeros (same-wave DS order)
    float4 x4 = *(const float4*)(xp);

    for (int t = 0; t < TT; t += 4) {
        const int tn = (t + 4) & (TT - 1);        // branchless wrap prefetch
        float4 x4n = *(const float4*)(xp + tn);
        float outv[4];
#pragma unroll
        for (int u = 0; u < 4; ++u) {
            float xv = (u == 0) ? x4.x : (u == 1) ? x4.y : (u == 2) ? x4.z : x4.w;

            // 4 gate dots over h (fp16 in, fp32 accum), FOUR depth-4 chains
            // each (stride-4 pair assignment) to cut loop-carried latency.
            float sI0 = fmaf(xv, aI, cI), sI1 = 0.f, sI2 = 0.f, sI3 = 0.f;
            float sF0 = fmaf(xv, aF, cF), sF1 = 0.f, sF2 = 0.f, sF3 = 0.f;
            float sG0 = fmaf(xv, aG, cG), sG1 = 0.f, sG2 = 0.f, sG3 = 0.f;
            float sO0 = fmaf(xv, aO, cO), sO1 = 0.f, sO2 = 0.f, sO3 = 0.f;
#pragma unroll
            for (int k = 0; k < 16; k += 4) {
                h2 h0 = hcur.v[k],     h1 = hcur.v[k + 1];
                h2 h2_ = hcur.v[k + 2], h3 = hcur.v[k + 3];
                sI0 = __builtin_amdgcn_fdot2(wI[k],     h0,  sI0, false);
                sF0 = __builtin_amdgcn_fdot2(wF[k],     h0,  sF0, false);
                sG0 = __builtin_amdgcn_fdot2(wG[k],     h0,  sG0, false);
                sO0 = __builtin_amdgcn_fdot2(wO[k],     h0,  sO0, false);
                sI1 = __builtin_amdgcn_fdot2(wI[k + 1], h1,  sI1, false);
                sF1 = __builtin_amdgcn_fdot2(wF[k + 1], h1,  sF1, false);
                sG1 = __builtin_amdgcn_fdot2(wG[k + 1], h1,  sG1, false);
                sO1 = __builtin_amdgcn_fdot2(wO[k + 1], h1,  sO1, false);
                sI2 = __builtin_amdgcn_fdot2(wI[k + 2], h2_, sI2, false);
                sF2 = __builtin_amdgcn_fdot2(wF[k + 2], h2_, sF2, false);
                sG2 = __builtin_amdgcn_fdot2(wG[k + 2], h2_, sG2, false);
                sO2 = __builtin_amdgcn_fdot2(wO[k + 2], h2_, sO2, false);
                sI3 = __builtin_amdgcn_fdot2(wI[k + 3], h3,  sI3, false);
                sF3 = __builtin_amdgcn_fdot2(wF[k + 3], h3,  sF3, false);
                sG3 = __builtin_amdgcn_fdot2(wG[k + 3], h3,  sG3, false);
                sO3 = __builtin_amdgcn_fdot2(wO[k + 3], h3,  sO3, false);
            }
            float gIv = (sI0 + sI1) + (sI2 + sI3);
            float gFv = (sF0 + sF1) + (sF2 + sF3);
            float gGv = (sG0 + sG1) + (sG2 + sG3);
            float gOv = (sO0 + sO1) + (sO2 + sO3);

            float iv = gate_eval(gIv, -LOG2E, 1.0f, 0.0f);
            float fv = gate_eval(gFv, -LOG2E, 1.0f, 0.0f);
            float gv = gate_eval(gGv, -2.0f * LOG2E, 2.0f, -1.0f);
            float ov = gate_eval(gOv, -LOG2E, 1.0f, 0.0f);

            c = fmaf(fv, c, iv * gv);
            float th = gate_eval(c, -2.0f * LOG2E, 2.0f, -1.0f); // tanh(c)
            float h = ov * th;

            // publish h, then issue next gather; DPP reduce overlaps DS latency
            hbase[j] = (_Float16)h;
            hcur = gather_h(hbase);

            // fused output projection: width-32 reduce on VALU via DPP.
            float po = woj * h;
            po = dpp_add<0x111>(po);
            po = dpp_add<0x112>(po);
            po = dpp_add<0x114>(po);
            po = dpp_add<0x118>(po);
            po = dpp_add<0x142>(po);   // row_bcast15 -> lane 31/63 hold the sum
            outv[u] = po + bo0;
        }
        if ((lane & 31) == 31) {
            *(float4*)(op + t) = make_float4(outv[0], outv[1], outv[2], outv[3]);
        }
        x4 = x4n;
    }
}

extern "C" void kernel_launch(void* const* d_in, const int* in_sizes, int n_in,
                              void* d_out, int out_size, void* d_ws, size_t ws_size,
                              hipStream_t stream) {
    const float* x_seq = (const float*)d_in[0];
    const float* Wp    = (const float*)d_in[1];
    const float* bp    = (const float*)d_in[2];
    const float* W_ih  = (const float*)d_in[3];
    const float* W_hh  = (const float*)d_in[4];
    const float* b_ih  = (const float*)d_in[5];
    const float* b_hh  = (const float*)d_in[6];
    const float* Wo    = (const float*)d_in[7];
    const float* bo    = (const float*)d_in[8];
    float* out = (float*)d_out;

    dim3 grid(BB / 8);   // 4 waves/block, 2 batch elements/wave
    dim3 block(256);
    lstm_fused_kernel<<<grid, block, 0, stream>>>(
        x_seq, Wp, bp, W_ih, W_hh, b_ih, b_hh, Wo, bo, out);
}

// Round 11
// 691.123 us; speedup vs baseline: 1.0410x; 1.0410x over previous
//
#include <hip/hip_runtime.h>

// OnlineDenoisingAutoencoder: LSTM(B=2048, T=2048, in=1, proj=16, H=32)
// R11 = R6 (champion, 670us) with ONE change: recurrent dots switched from
// v_dot2_f32_f16 (measured ~4cyc, same MAC rate as scalar fma) to
// v_pk_fma_f16 (full-rate packed fp16, 2 MACs / 2 cyc => halves dot issue
// 256->128 cyc/wave-step). Per gate: two depth-8 packed fp16 accum chains,
// combined via v_pk_add_f16 + one fdot2 against (1,1) seeded with the fp32
// x-term (cvt+reduce+bias in one op). Cell state c stays fp32.
// Layout (R6): 2 batches/wave (half=batch, j=lane&31), all 4 gates per lane,
// fp16 h via per-wave LDS (write + 4x ds_read_b128, no syncthreads), f32
// transcendentals, DPP output reduce, lane 31/63 stores. 1024 waves.
// History: R2 864 fp32; R3 pk_fma_f32 not 2x (996); R4 readlane (1034);
// R6 670; R7 reg-gather (731, stall=DS-latency-equivalent either way);
// R8 TLP=2 dup (875); R9 f16 trans marshaling (716); R10 depth-4 chains (719).

#define BB 2048
#define TT 2048
#define HH 32

typedef _Float16 h2 __attribute__((ext_vector_type(2)));

__device__ __forceinline__ float gate_eval(float x, float m, float a, float b) {
    // a * (1 / (1 + 2^(m*x))) + b ; sigmoid: m=-log2e,a=1,b=0 ; tanh: m=-2log2e,a=2,b=-1
    float e = __builtin_amdgcn_exp2f(x * m);
    float r = __builtin_amdgcn_rcpf(1.0f + e);
    return fmaf(a, r, b);
}

template <int CTRL>
__device__ __forceinline__ float dpp_add(float v) {
    int s = __builtin_amdgcn_update_dpp(0, __float_as_int(v), CTRL, 0xf, 0xf, true);
    return v + __int_as_float(s);
}

struct HVec { h2 v[16]; };

__device__ __forceinline__ HVec gather_h(const _Float16* base) {
    const float4* p = (const float4*)base;   // 64 B = 4 x ds_read_b128 (broadcast)
    float4 q0 = p[0], q1 = p[1], q2 = p[2], q3 = p[3];
    HVec r;
    r.v[0]  = __builtin_bit_cast(h2, q0.x); r.v[1]  = __builtin_bit_cast(h2, q0.y);
    r.v[2]  = __builtin_bit_cast(h2, q0.z); r.v[3]  = __builtin_bit_cast(h2, q0.w);
    r.v[4]  = __builtin_bit_cast(h2, q1.x); r.v[5]  = __builtin_bit_cast(h2, q1.y);
    r.v[6]  = __builtin_bit_cast(h2, q1.z); r.v[7]  = __builtin_bit_cast(h2, q1.w);
    r.v[8]  = __builtin_bit_cast(h2, q2.x); r.v[9]  = __builtin_bit_cast(h2, q2.y);
    r.v[10] = __builtin_bit_cast(h2, q2.z); r.v[11] = __builtin_bit_cast(h2, q2.w);
    r.v[12] = __builtin_bit_cast(h2, q3.x); r.v[13] = __builtin_bit_cast(h2, q3.y);
    r.v[14] = __builtin_bit_cast(h2, q3.z); r.v[15] = __builtin_bit_cast(h2, q3.w);
    return r;
}

__global__ __launch_bounds__(256) void lstm_fused_kernel(
    const float* __restrict__ x_seq,  // [B,T,1]
    const float* __restrict__ Wp,     // [16,1]
    const float* __restrict__ bp,     // [16]
    const float* __restrict__ W_ih,   // [128,16]
    const float* __restrict__ W_hh,   // [128,32]
    const float* __restrict__ b_ih,   // [128]
    const float* __restrict__ b_hh,   // [128]
    const float* __restrict__ Wo,     // [1,32]
    const float* __restrict__ bo,     // [1]
    float* __restrict__ out)          // [B,T,1] fp32
{
    const int tid  = threadIdx.x;
    const int wave = tid >> 6;
    const int lane = tid & 63;
    const int half = lane >> 5;      // which of the wave's 2 batch elements
    const int j    = lane & 31;      // hidden index this lane owns
    const int b    = blockIdx.x * 8 + wave * 2 + half;

    // PyTorch gate row order: i=[0,32), f=[32,64), g=[64,96), o=[96,128)
    const int rI = j, rF = HH + j, rG = 2 * HH + j, rO = 3 * HH + j;

    // ---- W_hh rows (4 gates) into registers as packed fp16 pairs ----
    h2 wI[16], wF[16], wG[16], wO[16];
    {
        const float2* pI = (const float2*)(W_hh + rI * HH);
        const float2* pF = (const float2*)(W_hh + rF * HH);
        const float2* pG = (const float2*)(W_hh + rG * HH);
        const float2* pO = (const float2*)(W_hh + rO * HH);
#pragma unroll
        for (int k = 0; k < 16; ++k) {
            float2 a = pI[k], f = pF[k], g = pG[k], o = pO[k];
            wI[k].x = (_Float16)a.x; wI[k].y = (_Float16)a.y;
            wF[k].x = (_Float16)f.x; wF[k].y = (_Float16)f.y;
            wG[k].x = (_Float16)g.x; wG[k].y = (_Float16)g.y;
            wO[k].x = (_Float16)o.x; wO[k].y = (_Float16)o.y;
        }
    }

    // ---- collapse input pipeline: pre-act = dot + x*a + c (INPUT_DIM==1) ----
    float aI = 0.f, cI = 0.f, aF = 0.f, cF = 0.f;
    float aG = 0.f, cG = 0.f, aO = 0.f, cO = 0.f;
#pragma unroll
    for (int p = 0; p < 16; ++p) {
        float wpv = Wp[p], bpv = bp[p];
        float wi = W_ih[rI * 16 + p], wf = W_ih[rF * 16 + p];
        float wg = W_ih[rG * 16 + p], wo_ = W_ih[rO * 16 + p];
        aI = fmaf(wi, wpv, aI);  cI = fmaf(wi, bpv, cI);
        aF = fmaf(wf, wpv, aF);  cF = fmaf(wf, bpv, cF);
        aG = fmaf(wg, wpv, aG);  cG = fmaf(wg, bpv, cG);
        aO = fmaf(wo_, wpv, aO); cO = fmaf(wo_, bpv, cO);
    }
    cI += b_ih[rI] + b_hh[rI];
    cF += b_ih[rF] + b_hh[rF];
    cG += b_ih[rG] + b_hh[rG];
    cO += b_ih[rO] + b_hh[rO];

    const float LOG2E = 1.44269504088896340736f;
    const float woj = Wo[j];
    const float bo0 = bo[0];
    const h2 kOnes = {(_Float16)1.0f, (_Float16)1.0f};

    // per-(wave,batch) h buffer, fp16, 64 B each
    __shared__ __align__(16) _Float16 hsh[4][2][HH];
    _Float16* hbase = &hsh[wave][half][0];
    hbase[j] = (_Float16)0.0f;

    float c = 0.0f;
    const float* xp = x_seq + (size_t)b * TT;
    float* op = out + (size_t)b * TT;

    HVec hcur = gather_h(hbase);            // zeros (same-wave DS order)
    float4 x4 = *(const float4*)(xp);

    for (int t = 0; t < TT; t += 4) {
        const int tn = (t + 4 < TT) ? (t + 4) : t;
        float4 x4n = *(const float4*)(xp + tn);   // prefetch next group
        float outv[4];
#pragma unroll
        for (int u = 0; u < 4; ++u) {
            float xv = (u == 0) ? x4.x : (u == 1) ? x4.y : (u == 2) ? x4.z : x4.w;

            // 4 gate dots over h: v_pk_fma_f16 (full-rate, 2 MACs/instr),
            // two depth-8 packed accum chains per gate.
            h2 accI0 = {0, 0}, accI1 = {0, 0};
            h2 accF0 = {0, 0}, accF1 = {0, 0};
            h2 accG0 = {0, 0}, accG1 = {0, 0};
            h2 accO0 = {0, 0}, accO1 = {0, 0};
#pragma unroll
            for (int k = 0; k < 16; k += 2) {
                h2 h0 = hcur.v[k], h1 = hcur.v[k + 1];
                accI0 = __builtin_elementwise_fma(wI[k],     h0, accI0);
                accF0 = __builtin_elementwise_fma(wF[k],     h0, accF0);
                accG0 = __builtin_elementwise_fma(wG[k],     h0, accG0);
                accO0 = __builtin_elementwise_fma(wO[k],     h0, accO0);
                accI1 = __builtin_elementwise_fma(wI[k + 1], h1, accI1);
                accF1 = __builtin_elementwise_fma(wF[k + 1], h1, accF1);
                accG1 = __builtin_elementwise_fma(wG[k + 1], h1, accG1);
                accO1 = __builtin_elementwise_fma(wO[k + 1], h1, accO1);
            }
            // combine: pk_add, then fdot2 against (1,1) seeded with fp32 x-term
            h2 sI = accI0 + accI1;
            h2 sF = accF0 + accF1;
            h2 sG = accG0 + accG1;
            h2 sO = accO0 + accO1;
            float gIv = __builtin_amdgcn_fdot2(sI, kOnes, fmaf(xv, aI, cI), false);
            float gFv = __builtin_amdgcn_fdot2(sF, kOnes, fmaf(xv, aF, cF), false);
            float gGv = __builtin_amdgcn_fdot2(sG, kOnes, fmaf(xv, aG, cG), false);
            float gOv = __builtin_amdgcn_fdot2(sO, kOnes, fmaf(xv, aO, cO), false);

            float iv = gate_eval(gIv, -LOG2E, 1.0f, 0.0f);
            float fv = gate_eval(gFv, -LOG2E, 1.0f, 0.0f);
            float gv = gate_eval(gGv, -2.0f * LOG2E, 2.0f, -1.0f);
            float ov = gate_eval(gOv, -LOG2E, 1.0f, 0.0f);

            c = fmaf(fv, c, iv * gv);
            float th = gate_eval(c, -2.0f * LOG2E, 2.0f, -1.0f); // tanh(c)
            float h = ov * th;

            // publish h, then issue next gather; DPP reduce overlaps DS latency
            hbase[j] = (_Float16)h;
            hcur = gather_h(hbase);

            // fused output projection: width-32 reduce on VALU via DPP.
            float po = woj * h;
            po = dpp_add<0x111>(po);
            po = dpp_add<0x112>(po);
            po = dpp_add<0x114>(po);
            po = dpp_add<0x118>(po);
            po = dpp_add<0x142>(po);   // row_bcast15 -> lane 31/63 hold the sum
            outv[u] = po + bo0;
        }
        if ((lane & 31) == 31) {
            *(float4*)(op + t) = make_float4(outv[0], outv[1], outv[2], outv[3]);
        }
        x4 = x4n;
    }
}

extern "C" void kernel_launch(void* const* d_in, const int* in_sizes, int n_in,
                              void* d_out, int out_size, void* d_ws, size_t ws_size,
                              hipStream_t stream) {
    const float* x_seq = (const float*)d_in[0];
    const float* Wp    = (const float*)d_in[1];
    const float* bp    = (const float*)d_in[2];
    const float* W_ih  = (const float*)d_in[3];
    const float* W_hh  = (const float*)d_in[4];
    const float* b_ih  = (const float*)d_in[5];
    const float* b_hh  = (const float*)d_in[6];
    const float* Wo    = (const float*)d_in[7];
    const float* bo    = (const float*)d_in[8];
    float* out = (float*)d_out;

    dim3 grid(BB / 8);   // 4 waves/block, 2 batch elements/wave
    dim3 block(256);
    lstm_fused_kernel<<<grid, block, 0, stream>>>(
        x_seq, Wp, bp, W_ih, W_hh, b_ih, b_hh, Wo, bo, out);
}